// Round 2
// baseline (323.710 us; speedup 1.0000x reference)
//
#include <hip/hip_runtime.h>
#include <math.h>

// ---------------- problem constants ----------------
#define BATCH   8192
#define F1      256
#define NT      128     // trees
#define TDEPTH  6
#define TD      768     // NT*TDEPTH (sel columns)
#define TOUT    128     // NT * O
#define BN_EPS  1e-5f

// fused GEMM+tree tile
#define BM      64
#define BN      96      // 16 trees * 6
#define BK      32
#define TREES_PER_BLK 16

__device__ __forceinline__ float sigmoidf_(float x) {
    return 1.0f / (1.0f + expf(-x));
}

// ---------------- zero scratch ----------------
__global__ void zero_kernel(float* __restrict__ p, int n) {
    int i = blockIdx.x * 256 + threadIdx.x;
    if (i < n) p[i] = 0.0f;
}

// ---------------- softmax over last axis, write TRANSPOSED ----------------
// src: [768][F], dst: [F][768]  (dst[f*TD + r])
__global__ __launch_bounds__(256)
void softmax_t_kernel(const float* __restrict__ src, float* __restrict__ dst, int F) {
    __shared__ float red[8];
    const int r = blockIdx.x;          // 0..767
    const int f = threadIdx.x;         // 0..255
    float v = (f < F) ? src[(size_t)r * F + f] : -INFINITY;

    float m = v;
    #pragma unroll
    for (int o = 32; o > 0; o >>= 1) m = fmaxf(m, __shfl_down(m, o, 64));
    const int lane = f & 63, wv = f >> 6;
    if (lane == 0) red[wv] = m;
    __syncthreads();
    if (f == 0) {
        float mm = red[0];
        for (int i = 1; i < 4; ++i) mm = fmaxf(mm, red[i]);
        red[0] = mm;
    }
    __syncthreads();
    m = red[0];
    __syncthreads();

    float e = (f < F) ? expf(v - m) : 0.0f;
    float s = e;
    #pragma unroll
    for (int o = 32; o > 0; o >>= 1) s += __shfl_down(s, o, 64);
    if (lane == 0) red[4 + wv] = s;
    __syncthreads();
    if (f == 0) {
        float ss = red[4];
        for (int i = 1; i < 4; ++i) ss += red[4 + i];
        red[4] = ss;
    }
    __syncthreads();
    s = red[4];

    if (f < F) dst[(size_t)f * TD + r] = e / s;
}

// ---------------- fused GEMM + oblivious-tree layer ----------------
// sel[b][t*6+d] = sum_k A'[b][k] * Bm[k][t*6+d]   (A' = relu(A*scale+shift) if BN_FUSE)
// then dec = sigmoid((sel - th)*exp(lt)); leaf expansion; h[b][t] = leaf . lr[t]
// Also accumulates per-tree batch sum/sumsq for BN-train.
// Block: 256 threads = 16 (m-groups of 4 rows) x 16 trees. Tile 64x96, BK=32.
template<int K, bool BN_FUSE>
__global__ __launch_bounds__(256)
void gemm_tree_kernel(const float* __restrict__ A, const float* __restrict__ Bm,
                      const float* __restrict__ th, const float* __restrict__ lt,
                      const float* __restrict__ lr,
                      float* __restrict__ h, float* __restrict__ bsum, float* __restrict__ bsq,
                      const float* __restrict__ scale, const float* __restrict__ shift) {
    __shared__ float As[BK][68];        // [k][m], row stride 68 (16B-aligned rows)
    __shared__ float Bs[BK][BN];        // [k][n]
    __shared__ float lrs[TREES_PER_BLK * 64];
    __shared__ float ths[TREES_PER_BLK * 6], es[TREES_PER_BLK * 6];
    __shared__ float red1[4][TREES_PER_BLK], red2[4][TREES_PER_BLK];

    const int tree_base = blockIdx.x * TREES_PER_BLK;
    const int bn = blockIdx.x * BN;
    const int bm = blockIdx.y * BM;
    const int tid = threadIdx.x;
    const int tt = tid & 15;            // tree within block
    const int mt = tid >> 4;            // m-group (4 rows)
    const int m0 = mt * 4;

    // stage tree params
    #pragma unroll
    for (int i = 0; i < 4; ++i) lrs[tid + 256 * i] = lr[tree_base * 64 + tid + 256 * i];
    if (tid < TREES_PER_BLK * 6) {
        ths[tid] = th[tree_base * 6 + tid];
        es[tid]  = expf(lt[tree_base * 6 + tid]);
    }

    float acc[4][6] = {};

    for (int k0 = 0; k0 < K; k0 += BK) {
        __syncthreads();
        // A tile 64x32 -> transposed into As[k][m]
        #pragma unroll
        for (int p = 0; p < 2; ++p) {
            const int e = p * 1024 + tid * 4;
            const int r  = e >> 5;      // 0..63
            const int kk = e & 31;      // multiple of 4
            float4 v = *reinterpret_cast<const float4*>(&A[(size_t)(bm + r) * K + k0 + kk]);
            if (BN_FUSE) {
                v.x = fmaxf(fmaf(v.x, scale[k0 + kk + 0], shift[k0 + kk + 0]), 0.0f);
                v.y = fmaxf(fmaf(v.y, scale[k0 + kk + 1], shift[k0 + kk + 1]), 0.0f);
                v.z = fmaxf(fmaf(v.z, scale[k0 + kk + 2], shift[k0 + kk + 2]), 0.0f);
                v.w = fmaxf(fmaf(v.w, scale[k0 + kk + 3], shift[k0 + kk + 3]), 0.0f);
            }
            As[kk + 0][r] = v.x;
            As[kk + 1][r] = v.y;
            As[kk + 2][r] = v.z;
            As[kk + 3][r] = v.w;
        }
        // B tile 32x96: 768 float4s over 256 threads
        #pragma unroll
        for (int p = 0; p < 3; ++p) {
            const int q    = p * 256 + tid;     // 0..767
            const int row  = q / 24;            // 0..31
            const int col4 = (q % 24) * 4;      // 0..92
            *reinterpret_cast<float4*>(&Bs[row][col4]) =
                *reinterpret_cast<const float4*>(&Bm[(size_t)(k0 + row) * TD + bn + col4]);
        }
        __syncthreads();

        #pragma unroll
        for (int kk = 0; kk < BK; ++kk) {
            const float4 a = *reinterpret_cast<const float4*>(&As[kk][m0]);
            const float av[4] = {a.x, a.y, a.z, a.w};
            float bv[6];
            #pragma unroll
            for (int j = 0; j < 6; ++j) bv[j] = Bs[kk][tt * 6 + j];
            #pragma unroll
            for (int i = 0; i < 4; ++i)
                #pragma unroll
                for (int j = 0; j < 6; ++j)
                    acc[i][j] = fmaf(av[i], bv[j], acc[i][j]);
        }
    }

    // ---- tree epilogue: 4 rows, 1 tree per thread ----
    const int t = tree_base + tt;
    float s1 = 0.0f, s2 = 0.0f;
    #pragma unroll
    for (int i = 0; i < 4; ++i) {
        float dec[6];
        #pragma unroll
        for (int d = 0; d < 6; ++d)
            dec[d] = sigmoidf_((acc[i][d] - ths[tt * 6 + d]) * es[tt * 6 + d]);

        float a1[2], a2[4], a3[8], a4[16], a5[32];
        a1[0] = 1.0f - dec[0]; a1[1] = dec[0];
        #pragma unroll
        for (int q = 0; q < 2; ++q)  { a2[2*q] = a1[q]*(1.0f-dec[1]); a2[2*q+1] = a1[q]*dec[1]; }
        #pragma unroll
        for (int q = 0; q < 4; ++q)  { a3[2*q] = a2[q]*(1.0f-dec[2]); a3[2*q+1] = a2[q]*dec[2]; }
        #pragma unroll
        for (int q = 0; q < 8; ++q)  { a4[2*q] = a3[q]*(1.0f-dec[3]); a4[2*q+1] = a3[q]*dec[3]; }
        #pragma unroll
        for (int q = 0; q < 16; ++q) { a5[2*q] = a4[q]*(1.0f-dec[4]); a5[2*q+1] = a4[q]*dec[4]; }

        float out = 0.0f;
        const float d5 = dec[5], nd5 = 1.0f - dec[5];
        #pragma unroll
        for (int p = 0; p < 32; ++p)
            out += a5[p] * (lrs[tt * 64 + 2*p] * nd5 + lrs[tt * 64 + 2*p + 1] * d5);

        h[(size_t)(bm + m0 + i) * TOUT + t] = out;
        s1 += out;
        s2 += out * out;
    }

    // ---- BN stats: reduce over mt (4 per wave via lane offsets 16/32), then waves ----
    s1 += __shfl_down(s1, 32, 64); s1 += __shfl_down(s1, 16, 64);
    s2 += __shfl_down(s2, 32, 64); s2 += __shfl_down(s2, 16, 64);
    const int wave = tid >> 6;
    if ((tid & 63) < 16) { red1[wave][tt] = s1; red2[wave][tt] = s2; }
    __syncthreads();
    if (tid < TREES_PER_BLK) {
        float S = red1[0][tid] + red1[1][tid] + red1[2][tid] + red1[3][tid];
        float Q = red2[0][tid] + red2[1][tid] + red2[2][tid] + red2[3][tid];
        atomicAdd(&bsum[tree_base + tid], S);
        atomicAdd(&bsq[tree_base + tid], Q);
    }
}

// ---------------- BN finalize: scale/shift per channel ----------------
__global__ void bn_finalize_kernel(const float* __restrict__ bsum, const float* __restrict__ bsq,
                                   const float* __restrict__ g, const float* __restrict__ be,
                                   float* __restrict__ scale, float* __restrict__ shift) {
    const int t = threadIdx.x;   // 128
    const float inv = 1.0f / (float)BATCH;
    const float mu  = bsum[t] * inv;
    float var = bsq[t] * inv - mu * mu;
    var = fmaxf(var, 0.0f);
    const float sc = g[t] / sqrtf(var + BN_EPS);
    scale[t] = sc;
    shift[t] = be[t] - mu * sc;
}

// ---------------- final: BN+ReLU -> [128x64] -> ReLU -> [64x1] ----------------
__global__ __launch_bounds__(256)
void final_kernel(const float* __restrict__ h2, const float* __restrict__ scale,
                  const float* __restrict__ shift,
                  const float* __restrict__ w1, const float* __restrict__ b1,
                  const float* __restrict__ w2, const float* __restrict__ b2,
                  float* __restrict__ out) {
    __shared__ float w1s[128 * 64];
    __shared__ float w2s[64], b1s[64];
    const int tid = threadIdx.x;
    for (int i = tid; i < 128 * 64; i += 256) w1s[i] = w1[i];
    if (tid < 64) { w2s[tid] = w2[tid]; b1s[tid] = b1[tid]; }
    __syncthreads();

    const int b = blockIdx.x * 256 + tid;
    float hl[128];
    #pragma unroll
    for (int k4 = 0; k4 < 32; ++k4) {
        const float4 v = *reinterpret_cast<const float4*>(&h2[(size_t)b * 128 + k4 * 4]);
        hl[k4*4+0] = fmaxf(fmaf(v.x, scale[k4*4+0], shift[k4*4+0]), 0.0f);
        hl[k4*4+1] = fmaxf(fmaf(v.y, scale[k4*4+1], shift[k4*4+1]), 0.0f);
        hl[k4*4+2] = fmaxf(fmaf(v.z, scale[k4*4+2], shift[k4*4+2]), 0.0f);
        hl[k4*4+3] = fmaxf(fmaf(v.w, scale[k4*4+3], shift[k4*4+3]), 0.0f);
    }

    float o = b2[0];
    for (int j = 0; j < 64; ++j) {
        float acc = b1s[j];
        #pragma unroll
        for (int k = 0; k < 128; ++k) acc = fmaf(hl[k], w1s[k * 64 + j], acc);
        o = fmaf(fmaxf(acc, 0.0f), w2s[j], o);
    }
    out[b] = o;
}

// ---------------- launch ----------------
extern "C" void kernel_launch(void* const* d_in, const int* in_sizes, int n_in,
                              void* d_out, int out_size, void* d_ws, size_t ws_size,
                              hipStream_t stream) {
    const float* x   = (const float*)d_in[0];
    const float* fs1 = (const float*)d_in[1];
    const float* th1 = (const float*)d_in[2];
    const float* lr1 = (const float*)d_in[3];
    const float* lt1 = (const float*)d_in[4];
    const float* g1  = (const float*)d_in[5];
    const float* be1 = (const float*)d_in[6];
    const float* fs2 = (const float*)d_in[7];
    const float* th2 = (const float*)d_in[8];
    const float* lr2 = (const float*)d_in[9];
    const float* lt2 = (const float*)d_in[10];
    const float* g2  = (const float*)d_in[11];
    const float* be2 = (const float*)d_in[12];
    const float* w1  = (const float*)d_in[13];
    const float* b1  = (const float*)d_in[14];
    const float* w2  = (const float*)d_in[15];
    const float* b2  = (const float*)d_in[16];

    float* ws = (float*)d_ws;
    float* fw1T  = ws;                        // 256*768 = 196608
    float* fw2T  = ws + 196608;               // 128*768 =  98304
    float* stats = ws + 294912;               // 512: sum1[128] sq1[128] sum2[128] sq2[128]
    float* ssbuf = ws + 295424;               // 512: scale1 shift1 scale2 shift2
    float* h1    = ws + 295936;               // 8192*128 = 1048576
    float* h2    = h1 + 1048576;              // 8192*128 = 1048576
    float* out   = (float*)d_out;

    zero_kernel<<<2, 256, 0, stream>>>(stats, 512);

    softmax_t_kernel<<<768, 256, 0, stream>>>(fs1, fw1T, 256);
    softmax_t_kernel<<<768, 256, 0, stream>>>(fs2, fw2T, 128);

    dim3 gt_grid(TD / BN, BATCH / BM);        // (8, 128)
    gemm_tree_kernel<256, false><<<gt_grid, 256, 0, stream>>>(
        x, fw1T, th1, lt1, lr1, h1, stats + 0, stats + 128, nullptr, nullptr);
    bn_finalize_kernel<<<1, 128, 0, stream>>>(stats + 0, stats + 128, g1, be1, ssbuf + 0, ssbuf + 128);

    gemm_tree_kernel<128, true><<<gt_grid, 256, 0, stream>>>(
        h1, fw2T, th2, lt2, lr2, h2, stats + 256, stats + 384, ssbuf + 0, ssbuf + 128);
    bn_finalize_kernel<<<1, 128, 0, stream>>>(stats + 256, stats + 384, g2, be2, ssbuf + 256, ssbuf + 384);

    final_kernel<<<BATCH / 256, 256, 0, stream>>>(h2, ssbuf + 256, ssbuf + 384, w1, b1, w2, b2, out);
}

// Round 4
// 237.986 us; speedup vs baseline: 1.3602x; 1.3602x over previous
//
#include <hip/hip_runtime.h>
#include <math.h>

// ---------------- problem constants ----------------
#define BATCH   8192
#define NT      128     // trees
#define TD      768     // NT*6 (sel columns)
#define TOUT    128     // NT * O
#define BN_EPS  1e-5f

// fused GEMM+tree tile
#define BM      128
#define BN      96      // 16 trees * 6
#define BK      32
#define BS_STRIDE 112   // Bs row stride (pad 96->112, 16B aligned)
#define LRS_STRIDE 66   // conflict-free lr stride

__device__ __forceinline__ float sigmoidf_(float x) {
    return 1.0f / (1.0f + expf(-x));
}

// ---------------- zero scratch ----------------
__global__ void zero_kernel(float* __restrict__ p, int n) {
    int i = blockIdx.x * 256 + threadIdx.x;
    if (i < n) p[i] = 0.0f;
}

// ---------------- softmax over last axis, write TRANSPOSED ----------------
// src: [768][F], dst: [F][768]  (dst[f*TD + r])
__global__ __launch_bounds__(256)
void softmax_t_kernel(const float* __restrict__ src, float* __restrict__ dst, int F) {
    __shared__ float red[8];
    const int r = blockIdx.x;          // 0..767
    const int f = threadIdx.x;         // 0..255
    float v = (f < F) ? src[(size_t)r * F + f] : -INFINITY;

    float m = v;
    #pragma unroll
    for (int o = 32; o > 0; o >>= 1) m = fmaxf(m, __shfl_down(m, o, 64));
    const int lane = f & 63, wv = f >> 6;
    if (lane == 0) red[wv] = m;
    __syncthreads();
    if (f == 0) {
        float mm = red[0];
        for (int i = 1; i < 4; ++i) mm = fmaxf(mm, red[i]);
        red[0] = mm;
    }
    __syncthreads();
    m = red[0];
    __syncthreads();

    float e = (f < F) ? expf(v - m) : 0.0f;
    float s = e;
    #pragma unroll
    for (int o = 32; o > 0; o >>= 1) s += __shfl_down(s, o, 64);
    if (lane == 0) red[4 + wv] = s;
    __syncthreads();
    if (f == 0) {
        float ss = red[4];
        for (int i = 1; i < 4; ++i) ss += red[4 + i];
        red[4] = ss;
    }
    __syncthreads();
    s = red[4];

    if (f < F) dst[(size_t)f * TD + r] = e / s;
}

// ---------------- fused GEMM + oblivious-tree layer ----------------
// Tile 128x96 (16 trees), BK=32, 256 threads; thread = 8 rows x 1 tree (6 cols).
// As: [k][m] stride 128, XOR-swizzled in 16B chunks (chunk ^= k>>2):
//   write + b128 read both conflict-free.
template<int K, bool BN_FUSE>
__global__ __launch_bounds__(256)
void gemm_tree_kernel(const float* __restrict__ A, const float* __restrict__ Bm,
                      const float* __restrict__ th, const float* __restrict__ lt,
                      const float* __restrict__ lr,
                      float* __restrict__ h, float* __restrict__ bsum, float* __restrict__ bsq,
                      const float* __restrict__ scale, const float* __restrict__ shift) {
    __shared__ float As[BK * BM];                 // swizzled [k][chunk^(k>>2)][4]
    __shared__ float Bs[BK][BS_STRIDE];
    __shared__ float lrs[16 * LRS_STRIDE];
    __shared__ float ths[96], es[96];
    __shared__ float red1[4][16], red2[4][16];

    const int tree_base = blockIdx.x * 16;
    const int bn = blockIdx.x * BN;
    const int bm = blockIdx.y * BM;
    const int tid = threadIdx.x;
    const int tt  = tid & 15;          // tree within block
    const int mt  = tid >> 4;          // m-group (8 rows)
    const int tt6 = tt * 6;
    const int tt66 = tt * LRS_STRIDE;
    const int mt2 = mt * 2;

    // stage tree params (lr at stride 66 -> conflict-free b64 reads later)
    for (int q = tid; q < 1024; q += 256)
        lrs[(q >> 6) * LRS_STRIDE + (q & 63)] = lr[tree_base * 64 + q];
    if (tid < 96) {
        ths[tid] = th[tree_base * 6 + tid];
        es[tid]  = expf(lt[tree_base * 6 + tid]);
    }

    float acc[8][6] = {};

    const int t7   = tid & 7;
    const int arow = tid >> 3;         // 0..31
    const int akk  = t7 * 4;           // k offset of this thread's A float4

    for (int k0 = 0; k0 < K; k0 += BK) {
        __syncthreads();
        // A tile 128x32 -> transposed+swizzled into As
        #pragma unroll
        for (int p = 0; p < 4; ++p) {
            const int r = p * 32 + arow;
            float4 v = *reinterpret_cast<const float4*>(&A[(size_t)(bm + r) * K + k0 + akk]);
            if (BN_FUSE) {
                v.x = fmaxf(fmaf(v.x, scale[k0 + akk + 0], shift[k0 + akk + 0]), 0.0f);
                v.y = fmaxf(fmaf(v.y, scale[k0 + akk + 1], shift[k0 + akk + 1]), 0.0f);
                v.z = fmaxf(fmaf(v.z, scale[k0 + akk + 2], shift[k0 + akk + 2]), 0.0f);
                v.w = fmaxf(fmaf(v.w, scale[k0 + akk + 3], shift[k0 + akk + 3]), 0.0f);
            }
            const int base = akk * BM + ((((r >> 2) ^ t7) << 2) | (r & 3));
            As[base          ] = v.x;
            As[base + BM     ] = v.y;
            As[base + 2 * BM ] = v.z;
            As[base + 3 * BM ] = v.w;
        }
        // B tile 32x96
        #pragma unroll
        for (int p = 0; p < 3; ++p) {
            const int q    = p * 256 + tid;     // 0..767
            const int row  = q / 24;
            const int col4 = (q % 24) * 4;
            *reinterpret_cast<float4*>(&Bs[row][col4]) =
                *reinterpret_cast<const float4*>(&Bm[(size_t)(k0 + row) * TD + bn + col4]);
        }
        __syncthreads();

        #pragma unroll
        for (int kk = 0; kk < BK; ++kk) {
            const int sw = kk >> 2;
            const float4 a0 = *reinterpret_cast<const float4*>(&As[kk * BM + (((mt2    ) ^ sw) << 2)]);
            const float4 a1 = *reinterpret_cast<const float4*>(&As[kk * BM + (((mt2 + 1) ^ sw) << 2)]);
            const float2 b0 = *reinterpret_cast<const float2*>(&Bs[kk][tt6    ]);
            const float2 b1 = *reinterpret_cast<const float2*>(&Bs[kk][tt6 + 2]);
            const float2 b2 = *reinterpret_cast<const float2*>(&Bs[kk][tt6 + 4]);
            const float av[8] = {a0.x, a0.y, a0.z, a0.w, a1.x, a1.y, a1.z, a1.w};
            const float bv[6] = {b0.x, b0.y, b1.x, b1.y, b2.x, b2.y};
            #pragma unroll
            for (int i = 0; i < 8; ++i)
                #pragma unroll
                for (int j = 0; j < 6; ++j)
                    acc[i][j] = fmaf(av[i], bv[j], acc[i][j]);
        }
    }

    // ---- tree epilogue: 8 rows, 1 tree per thread ----
    const int t = tree_base + tt;
    float s1 = 0.0f, s2 = 0.0f;
    #pragma unroll
    for (int i = 0; i < 8; ++i) {
        float dec[6];
        #pragma unroll
        for (int d = 0; d < 6; ++d)
            dec[d] = sigmoidf_((acc[i][d] - ths[tt6 + d]) * es[tt6 + d]);

        float a1r[2], a2r[4], a3r[8], a4r[16], a5r[32];
        a1r[0] = 1.0f - dec[0]; a1r[1] = dec[0];
        #pragma unroll
        for (int q = 0; q < 2; ++q)  { a2r[2*q] = a1r[q]*(1.0f-dec[1]); a2r[2*q+1] = a1r[q]*dec[1]; }
        #pragma unroll
        for (int q = 0; q < 4; ++q)  { a3r[2*q] = a2r[q]*(1.0f-dec[2]); a3r[2*q+1] = a2r[q]*dec[2]; }
        #pragma unroll
        for (int q = 0; q < 8; ++q)  { a4r[2*q] = a3r[q]*(1.0f-dec[3]); a4r[2*q+1] = a3r[q]*dec[3]; }
        #pragma unroll
        for (int q = 0; q < 16; ++q) { a5r[2*q] = a4r[q]*(1.0f-dec[4]); a5r[2*q+1] = a4r[q]*dec[4]; }

        float out = 0.0f;
        const float d5 = dec[5], nd5 = 1.0f - dec[5];
        #pragma unroll
        for (int p = 0; p < 32; ++p) {
            const float2 lp = *reinterpret_cast<const float2*>(&lrs[tt66 + 2 * p]);
            out += a5r[p] * (lp.x * nd5 + lp.y * d5);
        }

        h[(size_t)(bm + mt * 8 + i) * TOUT + t] = out;
        s1 += out;
        s2 += out * out;
    }

    // ---- BN stats reduce: mt groups within wave, then across waves ----
    s1 += __shfl_down(s1, 32, 64); s1 += __shfl_down(s1, 16, 64);
    s2 += __shfl_down(s2, 32, 64); s2 += __shfl_down(s2, 16, 64);
    const int wave = tid >> 6;
    if ((tid & 63) < 16) { red1[wave][tt] = s1; red2[wave][tt] = s2; }
    __syncthreads();
    if (tid < 16) {
        float S = red1[0][tid] + red1[1][tid] + red1[2][tid] + red1[3][tid];
        float Q = red2[0][tid] + red2[1][tid] + red2[2][tid] + red2[3][tid];
        atomicAdd(&bsum[tree_base + tid], S);
        atomicAdd(&bsq[tree_base + tid], Q);
    }
}

// ---------------- BN finalize: scale/shift per channel ----------------
__global__ void bn_finalize_kernel(const float* __restrict__ bsum, const float* __restrict__ bsq,
                                   const float* __restrict__ g, const float* __restrict__ be,
                                   float* __restrict__ scale, float* __restrict__ shift) {
    const int t = threadIdx.x;   // 128
    const float inv = 1.0f / (float)BATCH;
    const float mu  = bsum[t] * inv;
    float var = bsq[t] * inv - mu * mu;
    var = fmaxf(var, 0.0f);
    const float sc = g[t] / sqrtf(var + BN_EPS);
    scale[t] = sc;
    shift[t] = be[t] - mu * sc;
}

// ---------------- final: BN+ReLU -> [128x64] -> ReLU -> [64x1] ----------------
// Tiled GEMM: 64 rows/block, 256 thr = 16 j-groups x 16 m-groups, thread = 4 rows x 4 j.
__global__ __launch_bounds__(256)
void final_kernel(const float* __restrict__ h2, const float* __restrict__ scale,
                  const float* __restrict__ shift,
                  const float* __restrict__ w1, const float* __restrict__ b1,
                  const float* __restrict__ w2, const float* __restrict__ b2,
                  float* __restrict__ out) {
    __shared__ float Hs[32 * 64];      // [k][chunk ^ (k>>2)][4] swizzled
    __shared__ float Ws[128 * 64];     // full w1
    __shared__ float w2s[64], b1s[64];

    const int tid = threadIdx.x;
    const int jt = tid & 15, mt = tid >> 4;
    const int j0 = jt * 4;
    const int bm = blockIdx.x * 64;

    for (int q = tid * 4; q < 128 * 64; q += 1024)
        *reinterpret_cast<float4*>(&Ws[q]) = *reinterpret_cast<const float4*>(&w1[q]);
    if (tid < 64) { w2s[tid] = w2[tid]; b1s[tid] = b1[tid]; }

    float acc[4][4] = {};
    const int t7 = tid & 7;
    const int akk = t7 * 4;
    const int arow = tid >> 3;         // 0..31

    for (int k0 = 0; k0 < 128; k0 += 32) {
        __syncthreads();
        #pragma unroll
        for (int p = 0; p < 2; ++p) {
            const int r = p * 32 + arow;   // 0..63
            float4 v = *reinterpret_cast<const float4*>(&h2[(size_t)(bm + r) * 128 + k0 + akk]);
            v.x = fmaxf(fmaf(v.x, scale[k0 + akk + 0], shift[k0 + akk + 0]), 0.0f);
            v.y = fmaxf(fmaf(v.y, scale[k0 + akk + 1], shift[k0 + akk + 1]), 0.0f);
            v.z = fmaxf(fmaf(v.z, scale[k0 + akk + 2], shift[k0 + akk + 2]), 0.0f);
            v.w = fmaxf(fmaf(v.w, scale[k0 + akk + 3], shift[k0 + akk + 3]), 0.0f);
            const int base = akk * 64 + ((((r >> 2) ^ t7) << 2) | (r & 3));
            Hs[base      ] = v.x;
            Hs[base + 64 ] = v.y;
            Hs[base + 128] = v.z;
            Hs[base + 192] = v.w;
        }
        __syncthreads();
        #pragma unroll
        for (int kk = 0; kk < 32; ++kk) {
            const float4 hv = *reinterpret_cast<const float4*>(&Hs[kk * 64 + ((mt ^ (kk >> 2)) << 2)]);
            const float4 wv = *reinterpret_cast<const float4*>(&Ws[(k0 + kk) * 64 + j0]);
            const float hvv[4] = {hv.x, hv.y, hv.z, hv.w};
            const float wvv[4] = {wv.x, wv.y, wv.z, wv.w};
            #pragma unroll
            for (int i = 0; i < 4; ++i)
                #pragma unroll
                for (int j = 0; j < 4; ++j)
                    acc[i][j] = fmaf(hvv[i], wvv[j], acc[i][j]);
        }
    }

    const float b2v = b2[0];
    #pragma unroll
    for (int i = 0; i < 4; ++i) {
        float part = 0.0f;
        #pragma unroll
        for (int j = 0; j < 4; ++j)
            part += fmaxf(acc[i][j] + b1s[j0 + j], 0.0f) * w2s[j0 + j];
        part += __shfl_down(part, 8, 16);
        part += __shfl_down(part, 4, 16);
        part += __shfl_down(part, 2, 16);
        part += __shfl_down(part, 1, 16);
        if (jt == 0) out[bm + mt * 4 + i] = part + b2v;
    }
}

// ---------------- launch ----------------
extern "C" void kernel_launch(void* const* d_in, const int* in_sizes, int n_in,
                              void* d_out, int out_size, void* d_ws, size_t ws_size,
                              hipStream_t stream) {
    const float* x   = (const float*)d_in[0];
    const float* fs1 = (const float*)d_in[1];
    const float* th1 = (const float*)d_in[2];
    const float* lr1 = (const float*)d_in[3];
    const float* lt1 = (const float*)d_in[4];
    const float* g1  = (const float*)d_in[5];
    const float* be1 = (const float*)d_in[6];
    const float* fs2 = (const float*)d_in[7];
    const float* th2 = (const float*)d_in[8];
    const float* lr2 = (const float*)d_in[9];
    const float* lt2 = (const float*)d_in[10];
    const float* g2  = (const float*)d_in[11];
    const float* be2 = (const float*)d_in[12];
    const float* w1  = (const float*)d_in[13];
    const float* b1  = (const float*)d_in[14];
    const float* w2  = (const float*)d_in[15];
    const float* b2  = (const float*)d_in[16];

    float* ws = (float*)d_ws;
    float* fw1T  = ws;                        // 256*768 = 196608
    float* fw2T  = ws + 196608;               // 128*768 =  98304
    float* stats = ws + 294912;               // 512
    float* ssbuf = ws + 295424;               // 512
    float* h1    = ws + 295936;               // 8192*128
    float* h2    = h1 + 1048576;              // 8192*128
    float* out   = (float*)d_out;

    zero_kernel<<<2, 256, 0, stream>>>(stats, 512);

    softmax_t_kernel<<<768, 256, 0, stream>>>(fs1, fw1T, 256);
    softmax_t_kernel<<<768, 256, 0, stream>>>(fs2, fw2T, 128);

    dim3 gt_grid(TD / BN, BATCH / BM);        // (8, 64)
    gemm_tree_kernel<256, false><<<gt_grid, 256, 0, stream>>>(
        x, fw1T, th1, lt1, lr1, h1, stats + 0, stats + 128, nullptr, nullptr);
    bn_finalize_kernel<<<1, 128, 0, stream>>>(stats + 0, stats + 128, g1, be1, ssbuf + 0, ssbuf + 128);

    gemm_tree_kernel<128, true><<<gt_grid, 256, 0, stream>>>(
        h1, fw2T, th2, lt2, lr2, h2, stats + 256, stats + 384, ssbuf + 0, ssbuf + 128);
    bn_finalize_kernel<<<1, 128, 0, stream>>>(stats + 256, stats + 384, g2, be2, ssbuf + 256, ssbuf + 384);

    final_kernel<<<BATCH / 64, 256, 0, stream>>>(h2, ssbuf + 256, ssbuf + 384, w1, b1, w2, b2, out);
}

// Round 9
// 189.797 us; speedup vs baseline: 1.7056x; 1.2539x over previous
//
#include <hip/hip_runtime.h>
#include <math.h>

// ---------------- problem constants ----------------
#define BATCH   8192
#define NT      128
#define TD      768
#define TOUT    128
#define BN_EPS  1e-5f

typedef __attribute__((ext_vector_type(8))) short          bf16x8;
typedef __attribute__((ext_vector_type(4))) float          f32x4;
typedef __attribute__((ext_vector_type(8))) unsigned short u16x8;

__device__ __forceinline__ float sigmoidf_(float x) {
    return 1.0f / (1.0f + expf(-x));
}
__device__ __forceinline__ unsigned short f2bf(float f) {
    unsigned int u = __float_as_uint(f);
    u += 0x7fff + ((u >> 16) & 1);          // RNE
    return (unsigned short)(u >> 16);
}
__device__ __forceinline__ float bf2f(unsigned short b) {
    return __uint_as_float(((unsigned int)b) << 16);
}
__device__ __forceinline__ void split2(float x, unsigned short& hi, unsigned short& lo) {
    hi = f2bf(x);
    lo = f2bf(x - bf2f(hi));                 // x-hi exact in fp32
}
// fragment-packed offset for a [R][K] bf16 matrix:
// 1KB chunk per (16-row block, 32-k block); lane l = ((k>>3)&3)*16 + (r&15) holds 8 consecutive k.
// A and B share this k-slot permutation, so MFMA correctness is independent of HW k-order.
__device__ __forceinline__ int pk_off(int r, int k, int K) {
    return (r >> 4) * (K * 16) + (k >> 5) * 512 + (((k >> 3) & 3) << 7) + ((r & 15) << 3) + (k & 7);
}

// ---------------- softmax over last axis -> split-bf16, W^T frag-packed ----------------
// blocks 0..767: fs1 rows (F=256) -> w1h/w1l ; blocks 768..1535: fs2 rows (F=128) -> w2h/w2l
__global__ __launch_bounds__(256)
void softmax_pack_kernel(const float* __restrict__ fs1, const float* __restrict__ fs2,
                         unsigned short* __restrict__ w1h, unsigned short* __restrict__ w1l,
                         unsigned short* __restrict__ w2h, unsigned short* __restrict__ w2l) {
    __shared__ float red[8];
    int r = blockIdx.x;
    const float* src; unsigned short *dh, *dl; int F;
    if (r < TD) { F = 256; src = fs1 + (size_t)r * 256; dh = w1h; dl = w1l; }
    else        { r -= TD; F = 128; src = fs2 + (size_t)r * 128; dh = w2h; dl = w2l; }

    const int f = threadIdx.x;
    float v = (f < F) ? src[f] : -INFINITY;

    float m = v;
    #pragma unroll
    for (int o = 32; o > 0; o >>= 1) m = fmaxf(m, __shfl_down(m, o, 64));
    const int lane = f & 63, wv = f >> 6;
    if (lane == 0) red[wv] = m;
    __syncthreads();
    if (f == 0) {
        float mm = red[0];
        for (int i = 1; i < 4; ++i) mm = fmaxf(mm, red[i]);
        red[0] = mm;
    }
    __syncthreads();
    m = red[0];
    __syncthreads();

    float e = (f < F) ? expf(v - m) : 0.0f;
    float s = e;
    #pragma unroll
    for (int o = 32; o > 0; o >>= 1) s += __shfl_down(s, o, 64);
    if (lane == 0) red[4 + wv] = s;
    __syncthreads();
    if (f == 0) {
        float ss = red[4];
        for (int i = 1; i < 4; ++i) ss += red[4 + i];
        red[4] = ss;
    }
    __syncthreads();
    s = red[4];

    if (f < F) {
        unsigned short hi, lo;
        split2(e / s, hi, lo);
        const int off = pk_off(r, f, F);
        dh[off] = hi; dl[off] = lo;
    }
}

// ---------------- fp32 -> split-bf16 frag-packed (optionally BN+ReLU first) ----------------
template<int K, bool BN>
__global__ __launch_bounds__(256)
void convert_pack_kernel(const float* __restrict__ src,
                         unsigned short* __restrict__ dh, unsigned short* __restrict__ dl,
                         const float* __restrict__ scale, const float* __restrict__ shift,
                         float* __restrict__ stats_zero) {
    if (!BN && blockIdx.x == 0) {
        for (int i = threadIdx.x; i < 512; i += 256) stats_zero[i] = 0.0f;   // all 4 stat banks
    }
    const int gid = blockIdx.x * 256 + threadIdx.x;
    const int cpr = K / 8;
    const int r = gid / cpr, k = (gid % cpr) * 8;
    const float4 v0 = *reinterpret_cast<const float4*>(src + (size_t)r * K + k);
    const float4 v1 = *reinterpret_cast<const float4*>(src + (size_t)r * K + k + 4);
    float vv[8] = {v0.x, v0.y, v0.z, v0.w, v1.x, v1.y, v1.z, v1.w};
    u16x8 hh, ll;
    #pragma unroll
    for (int j = 0; j < 8; ++j) {
        float x = vv[j];
        if (BN) x = fmaxf(fmaf(x, scale[k + j], shift[k + j]), 0.0f);
        unsigned short hi, lo; split2(x, hi, lo);
        hh[j] = hi; ll[j] = lo;
    }
    const int off = pk_off(r, k, K);
    *reinterpret_cast<u16x8*>(dh + off) = hh;
    *reinterpret_cast<u16x8*>(dl + off) = ll;
}

// ---------------- fused MFMA GEMM + oblivious-tree layer ----------------
// C = A(split bf16, frag-packed) x W^T(split bf16, frag-packed); 3-product split accumulation.
// Block: 256 thr = 4 waves; tile 128 rows x 96 cols (16 trees); wave = 32 rows x 96 cols.
// No LDS in K-loop: every fragment is a per-lane contiguous 16B global load.
template<int K>
__global__ __launch_bounds__(256)
void gemm_tree_mfma_kernel(const unsigned short* __restrict__ Ah, const unsigned short* __restrict__ Al,
                           const unsigned short* __restrict__ Bh, const unsigned short* __restrict__ Bl,
                           const float* __restrict__ th, const float* __restrict__ lt,
                           const float* __restrict__ lr,
                           float* __restrict__ h, float* __restrict__ bsum, float* __restrict__ bsq) {
    __shared__ float sel_lds[4][16][104];     // per-wave transpose tile (row-pass of 16)
    __shared__ float lrs[16 * 66];
    __shared__ float ths[96], es[96];
    __shared__ float red1[4][16], red2[4][16];

    const int tid = threadIdx.x;
    const int wv = tid >> 6, l = tid & 63;
    const int tree_base = blockIdx.x * 16;
    const int bn16 = blockIdx.x * 6;          // W^T row-block base
    const int bm = blockIdx.y * 128;

    for (int q = tid; q < 1024; q += 256)
        lrs[(q >> 6) * 66 + (q & 63)] = lr[tree_base * 64 + q];
    if (tid < 96) {
        ths[tid] = th[tree_base * 6 + tid];
        es[tid]  = expf(lt[tree_base * 6 + tid]);
    }

    f32x4 acc[2][6];
    #pragma unroll
    for (int i = 0; i < 2; ++i)
        #pragma unroll
        for (int j = 0; j < 6; ++j)
            acc[i][j] = f32x4{0.f, 0.f, 0.f, 0.f};

    const int l8 = l * 8;
    const int rb0 = (bm >> 4) + wv * 2;
    const unsigned short* pAh = Ah + (size_t)rb0 * (K * 16) + l8;
    const unsigned short* pAl = Al + (size_t)rb0 * (K * 16) + l8;
    const unsigned short* pBh = Bh + (size_t)bn16 * (K * 16) + l8;
    const unsigned short* pBl = Bl + (size_t)bn16 * (K * 16) + l8;

    #pragma unroll 2
    for (int ks = 0; ks < K / 32; ++ks) {
        const int ko = ks * 512;
        const bf16x8 a0h = *reinterpret_cast<const bf16x8*>(pAh + ko);
        const bf16x8 a0l = *reinterpret_cast<const bf16x8*>(pAl + ko);
        const bf16x8 a1h = *reinterpret_cast<const bf16x8*>(pAh + K * 16 + ko);
        const bf16x8 a1l = *reinterpret_cast<const bf16x8*>(pAl + K * 16 + ko);
        #pragma unroll
        for (int nf = 0; nf < 6; ++nf) {
            const bf16x8 bh = *reinterpret_cast<const bf16x8*>(pBh + nf * (K * 16) + ko);
            const bf16x8 bl = *reinterpret_cast<const bf16x8*>(pBl + nf * (K * 16) + ko);
            acc[0][nf] = __builtin_amdgcn_mfma_f32_16x16x32_bf16(a0l, bh, acc[0][nf], 0, 0, 0);
            acc[0][nf] = __builtin_amdgcn_mfma_f32_16x16x32_bf16(a0h, bl, acc[0][nf], 0, 0, 0);
            acc[0][nf] = __builtin_amdgcn_mfma_f32_16x16x32_bf16(a0h, bh, acc[0][nf], 0, 0, 0);
            acc[1][nf] = __builtin_amdgcn_mfma_f32_16x16x32_bf16(a1l, bh, acc[1][nf], 0, 0, 0);
            acc[1][nf] = __builtin_amdgcn_mfma_f32_16x16x32_bf16(a1h, bl, acc[1][nf], 0, 0, 0);
            acc[1][nf] = __builtin_amdgcn_mfma_f32_16x16x32_bf16(a1h, bh, acc[1][nf], 0, 0, 0);
        }
    }

    __syncthreads();    // tree params staged by other waves

    // D layout (m89-verified): col = lane&15 (within 16-col frag), row = (lane>>4)*4 + reg
    const int t = l & 15, rg = l >> 4;
    const int t6 = t * 6, t66 = t * 66;
    float s1 = 0.f, s2 = 0.f;

    #pragma unroll
    for (int fm = 0; fm < 2; ++fm) {
        #pragma unroll
        for (int nf = 0; nf < 6; ++nf)
            #pragma unroll
            for (int r = 0; r < 4; ++r)
                sel_lds[wv][rg * 4 + r][nf * 16 + t] = acc[fm][nf][r];
        // wave-local LDS RAW: DS pipe is in-order per wave; compiler inserts lgkmcnt waits
        #pragma unroll
        for (int i = 0; i < 4; ++i) {
            const int row = rg + 4 * i;
            const float2 p0 = *reinterpret_cast<const float2*>(&sel_lds[wv][row][t6]);
            const float2 p1 = *reinterpret_cast<const float2*>(&sel_lds[wv][row][t6 + 2]);
            const float2 p2 = *reinterpret_cast<const float2*>(&sel_lds[wv][row][t6 + 4]);
            const float sv[6] = {p0.x, p0.y, p1.x, p1.y, p2.x, p2.y};
            float dec[6];
            #pragma unroll
            for (int d = 0; d < 6; ++d)
                dec[d] = sigmoidf_((sv[d] - ths[t6 + d]) * es[t6 + d]);

            float a1r[2], a2r[4], a3r[8], a4r[16], a5r[32];
            a1r[0] = 1.0f - dec[0]; a1r[1] = dec[0];
            #pragma unroll
            for (int q = 0; q < 2; ++q)  { a2r[2*q] = a1r[q]*(1.0f-dec[1]); a2r[2*q+1] = a1r[q]*dec[1]; }
            #pragma unroll
            for (int q = 0; q < 4; ++q)  { a3r[2*q] = a2r[q]*(1.0f-dec[2]); a3r[2*q+1] = a2r[q]*dec[2]; }
            #pragma unroll
            for (int q = 0; q < 8; ++q)  { a4r[2*q] = a3r[q]*(1.0f-dec[3]); a4r[2*q+1] = a3r[q]*dec[3]; }
            #pragma unroll
            for (int q = 0; q < 16; ++q) { a5r[2*q] = a4r[q]*(1.0f-dec[4]); a5r[2*q+1] = a4r[q]*dec[4]; }

            float out = 0.0f;
            const float d5 = dec[5], nd5 = 1.0f - dec[5];
            #pragma unroll
            for (int p = 0; p < 32; ++p) {
                const float2 lp = *reinterpret_cast<const float2*>(&lrs[t66 + 2 * p]);
                out += a5r[p] * (lp.x * nd5 + lp.y * d5);
            }

            h[(size_t)(bm + wv * 32 + fm * 16 + row) * TOUT + tree_base + t] = out;
            s1 += out;
            s2 += out * out;
        }
    }

    s1 += __shfl_down(s1, 32, 64); s1 += __shfl_down(s1, 16, 64);
    s2 += __shfl_down(s2, 32, 64); s2 += __shfl_down(s2, 16, 64);
    if (l < 16) { red1[wv][l] = s1; red2[wv][l] = s2; }
    __syncthreads();
    if (tid < 16) {
        const float S = red1[0][tid] + red1[1][tid] + red1[2][tid] + red1[3][tid];
        const float Q = red2[0][tid] + red2[1][tid] + red2[2][tid] + red2[3][tid];
        atomicAdd(&bsum[tree_base + tid], S);
        atomicAdd(&bsq[tree_base + tid], Q);
    }
}

// ---------------- BN finalize ----------------
__global__ void bn_finalize_kernel(const float* __restrict__ bsum, const float* __restrict__ bsq,
                                   const float* __restrict__ g, const float* __restrict__ be,
                                   float* __restrict__ scale, float* __restrict__ shift) {
    const int t = threadIdx.x;   // 128
    const float inv = 1.0f / (float)BATCH;
    const float mu  = bsum[t] * inv;
    float var = bsq[t] * inv - mu * mu;
    var = fmaxf(var, 0.0f);
    const float sc = g[t] / sqrtf(var + BN_EPS);
    scale[t] = sc;
    shift[t] = be[t] - mu * sc;
}

// ---------------- final: BN+ReLU -> [128x64] -> ReLU -> [64x1] ----------------
__global__ __launch_bounds__(256)
void final_kernel(const float* __restrict__ h2, const float* __restrict__ scale,
                  const float* __restrict__ shift,
                  const float* __restrict__ w1, const float* __restrict__ b1,
                  const float* __restrict__ w2, const float* __restrict__ b2,
                  float* __restrict__ out) {
    __shared__ float Hs[32 * 64];
    __shared__ float Ws[128 * 64];
    __shared__ float w2s[64], b1s[64];

    const int tid = threadIdx.x;
    const int jt = tid & 15, mt = tid >> 4;
    const int j0 = jt * 4;
    const int bm = blockIdx.x * 64;

    for (int q = tid * 4; q < 128 * 64; q += 1024)
        *reinterpret_cast<float4*>(&Ws[q]) = *reinterpret_cast<const float4*>(&w1[q]);
    if (tid < 64) { w2s[tid] = w2[tid]; b1s[tid] = b1[tid]; }

    float acc[4][4] = {};
    const int t7 = tid & 7;
    const int akk = t7 * 4;
    const int arow = tid >> 3;

    for (int k0 = 0; k0 < 128; k0 += 32) {
        __syncthreads();
        #pragma unroll
        for (int p = 0; p < 2; ++p) {
            const int r = p * 32 + arow;
            float4 v = *reinterpret_cast<const float4*>(&h2[(size_t)(bm + r) * 128 + k0 + akk]);
            v.x = fmaxf(fmaf(v.x, scale[k0 + akk + 0], shift[k0 + akk + 0]), 0.0f);
            v.y = fmaxf(fmaf(v.y, scale[k0 + akk + 1], shift[k0 + akk + 1]), 0.0f);
            v.z = fmaxf(fmaf(v.z, scale[k0 + akk + 2], shift[k0 + akk + 2]), 0.0f);
            v.w = fmaxf(fmaf(v.w, scale[k0 + akk + 3], shift[k0 + akk + 3]), 0.0f);
            const int base = akk * 64 + ((((r >> 2) ^ t7) << 2) | (r & 3));
            Hs[base      ] = v.x;
            Hs[base + 64 ] = v.y;
            Hs[base + 128] = v.z;
            Hs[base + 192] = v.w;
        }
        __syncthreads();
        #pragma unroll
        for (int kk = 0; kk < 32; ++kk) {
            const float4 hv = *reinterpret_cast<const float4*>(&Hs[kk * 64 + ((mt ^ (kk >> 2)) << 2)]);
            const float4 wv = *reinterpret_cast<const float4*>(&Ws[(k0 + kk) * 64 + j0]);
            const float hvv[4] = {hv.x, hv.y, hv.z, hv.w};
            const float wvv[4] = {wv.x, wv.y, wv.z, wv.w};
            #pragma unroll
            for (int i = 0; i < 4; ++i)
                #pragma unroll
                for (int j = 0; j < 4; ++j)
                    acc[i][j] = fmaf(hvv[i], wvv[j], acc[i][j]);
        }
    }

    const float b2v = b2[0];
    #pragma unroll
    for (int i = 0; i < 4; ++i) {
        float part = 0.0f;
        #pragma unroll
        for (int j = 0; j < 4; ++j)
            part += fmaxf(acc[i][j] + b1s[j0 + j], 0.0f) * w2s[j0 + j];
        part += __shfl_down(part, 8, 16);
        part += __shfl_down(part, 4, 16);
        part += __shfl_down(part, 2, 16);
        part += __shfl_down(part, 1, 16);
        if (jt == 0) out[bm + mt * 4 + i] = part + b2v;
    }
}

// ---------------- launch ----------------
extern "C" void kernel_launch(void* const* d_in, const int* in_sizes, int n_in,
                              void* d_out, int out_size, void* d_ws, size_t ws_size,
                              hipStream_t stream) {
    const float* x   = (const float*)d_in[0];
    const float* fs1 = (const float*)d_in[1];
    const float* th1 = (const float*)d_in[2];
    const float* lr1 = (const float*)d_in[3];
    const float* lt1 = (const float*)d_in[4];
    const float* g1  = (const float*)d_in[5];
    const float* be1 = (const float*)d_in[6];
    const float* fs2 = (const float*)d_in[7];
    const float* th2 = (const float*)d_in[8];
    const float* lr2 = (const float*)d_in[9];
    const float* lt2 = (const float*)d_in[10];
    const float* g2  = (const float*)d_in[11];
    const float* be2 = (const float*)d_in[12];
    const float* w1  = (const float*)d_in[13];
    const float* b1  = (const float*)d_in[14];
    const float* w2  = (const float*)d_in[15];
    const float* b2  = (const float*)d_in[16];

    float* ws    = (float*)d_ws;
    float* stats = ws;                        // 512
    float* ssbuf = ws + 512;                  // 512
    float* h1    = ws + 1024;                 // 8192*128
    float* h2    = h1 + 1048576;              // 8192*128
    unsigned short* us  = (unsigned short*)(h2 + 1048576);
    unsigned short* w1h = us;                 // 768*256
    unsigned short* w1l = w1h + 196608;
    unsigned short* w2h = w1l + 196608;       // 768*128
    unsigned short* w2l = w2h + 98304;
    unsigned short* xh  = w2l + 98304;        // 8192*256
    unsigned short* xl  = xh + 2097152;
    unsigned short* h1h = xl + 2097152;       // 8192*128
    unsigned short* h1l = h1h + 1048576;
    float* out = (float*)d_out;

    softmax_pack_kernel<<<1536, 256, 0, stream>>>(fs1, fs2, w1h, w1l, w2h, w2l);
    convert_pack_kernel<256, false><<<1024, 256, 0, stream>>>(x, xh, xl, nullptr, nullptr, stats);

    dim3 gg(TD / 96, BATCH / 128);            // (8, 64)
    gemm_tree_mfma_kernel<256><<<gg, 256, 0, stream>>>(
        xh, xl, w1h, w1l, th1, lt1, lr1, h1, stats + 0, stats + 128);
    bn_finalize_kernel<<<1, 128, 0, stream>>>(stats + 0, stats + 128, g1, be1, ssbuf + 0, ssbuf + 128);

    convert_pack_kernel<128, true><<<512, 256, 0, stream>>>(h1, h1h, h1l, ssbuf + 0, ssbuf + 128, nullptr);
    gemm_tree_mfma_kernel<128><<<gg, 256, 0, stream>>>(
        h1h, h1l, w2h, w2l, th2, lt2, lr2, h2, stats + 256, stats + 384);
    bn_finalize_kernel<<<1, 128, 0, stream>>>(stats + 256, stats + 384, g2, be2, ssbuf + 256, ssbuf + 384);

    final_kernel<<<BATCH / 64, 256, 0, stream>>>(h2, ssbuf + 256, ssbuf + 384, w1, b1, w2, b2, out);
}

// Round 12
// 188.077 us; speedup vs baseline: 1.7212x; 1.0091x over previous
//
#include <hip/hip_runtime.h>
#include <math.h>

// ---------------- problem constants ----------------
#define BATCH   8192
#define NT      128
#define TD      768
#define TOUT    128
#define BN_EPS  1e-5f

typedef __attribute__((ext_vector_type(8))) short          bf16x8;
typedef __attribute__((ext_vector_type(4))) float          f32x4;
typedef __attribute__((ext_vector_type(8))) unsigned short u16x8;

__device__ __forceinline__ float sigmoidf_(float x) {
    return 1.0f / (1.0f + expf(-x));
}
__device__ __forceinline__ unsigned short f2bf(float f) {
    unsigned int u = __float_as_uint(f);
    u += 0x7fff + ((u >> 16) & 1);          // RNE
    return (unsigned short)(u >> 16);
}
__device__ __forceinline__ float bf2f(unsigned short b) {
    return __uint_as_float(((unsigned int)b) << 16);
}
__device__ __forceinline__ void split2(float x, unsigned short& hi, unsigned short& lo) {
    hi = f2bf(x);
    lo = f2bf(x - bf2f(hi));                 // x-hi exact in fp32
}
// fragment-packed offset for a [R][K] bf16 matrix:
// 1KB chunk per (16-row block, 32-k block); lane l = ((k>>3)&3)*16 + (r&15) holds 8 consecutive k.
// A and B share this k-slot permutation, so MFMA correctness is independent of HW k-order.
__device__ __forceinline__ int pk_off(int r, int k, int K) {
    return (r >> 4) * (K * 16) + (k >> 5) * 512 + (((k >> 3) & 3) << 7) + ((r & 15) << 3) + (k & 7);
}

// ---------------- softmax over last axis -> split-bf16, W^T frag-packed ----------------
__global__ __launch_bounds__(256)
void softmax_pack_kernel(const float* __restrict__ fs1, const float* __restrict__ fs2,
                         unsigned short* __restrict__ w1h, unsigned short* __restrict__ w1l,
                         unsigned short* __restrict__ w2h, unsigned short* __restrict__ w2l) {
    __shared__ float red[8];
    int r = blockIdx.x;
    const float* src; unsigned short *dh, *dl; int F;
    if (r < TD) { F = 256; src = fs1 + (size_t)r * 256; dh = w1h; dl = w1l; }
    else        { r -= TD; F = 128; src = fs2 + (size_t)r * 128; dh = w2h; dl = w2l; }

    const int f = threadIdx.x;
    float v = (f < F) ? src[f] : -INFINITY;

    float m = v;
    #pragma unroll
    for (int o = 32; o > 0; o >>= 1) m = fmaxf(m, __shfl_down(m, o, 64));
    const int lane = f & 63, wv = f >> 6;
    if (lane == 0) red[wv] = m;
    __syncthreads();
    if (f == 0) {
        float mm = red[0];
        for (int i = 1; i < 4; ++i) mm = fmaxf(mm, red[i]);
        red[0] = mm;
    }
    __syncthreads();
    m = red[0];
    __syncthreads();

    float e = (f < F) ? expf(v - m) : 0.0f;
    float s = e;
    #pragma unroll
    for (int o = 32; o > 0; o >>= 1) s += __shfl_down(s, o, 64);
    if (lane == 0) red[4 + wv] = s;
    __syncthreads();
    if (f == 0) {
        float ss = red[4];
        for (int i = 1; i < 4; ++i) ss += red[4 + i];
        red[4] = ss;
    }
    __syncthreads();
    s = red[4];

    if (f < F) {
        unsigned short hi, lo;
        split2(e / s, hi, lo);
        const int off = pk_off(r, f, F);
        dh[off] = hi; dl[off] = lo;
    }
}

// ---------------- fp32 -> split-bf16 frag-packed (optional fused BN+ReLU from raw stats) ----------------
template<int K, bool BN>
__global__ __launch_bounds__(256)
void convert_pack_kernel(const float* __restrict__ src,
                         unsigned short* __restrict__ dh, unsigned short* __restrict__ dl,
                         const float* __restrict__ bsum, const float* __restrict__ bsq,
                         const float* __restrict__ g, const float* __restrict__ be,
                         float* __restrict__ stats_zero) {
    __shared__ float scs[128], shs[128];
    if (BN) {
        if (threadIdx.x < 128) {
            const float inv = 1.0f / (float)BATCH;
            const float mu = bsum[threadIdx.x] * inv;
            float var = bsq[threadIdx.x] * inv - mu * mu;
            var = fmaxf(var, 0.0f);
            const float s = g[threadIdx.x] / sqrtf(var + BN_EPS);
            scs[threadIdx.x] = s;
            shs[threadIdx.x] = be[threadIdx.x] - mu * s;
        }
        __syncthreads();
    } else {
        if (blockIdx.x == 0)
            for (int i = threadIdx.x; i < 512; i += 256) stats_zero[i] = 0.0f;
    }
    const int gid = blockIdx.x * 256 + threadIdx.x;
    const int cpr = K / 8;
    const int r = gid / cpr, k = (gid % cpr) * 8;
    const float4 v0 = *reinterpret_cast<const float4*>(src + (size_t)r * K + k);
    const float4 v1 = *reinterpret_cast<const float4*>(src + (size_t)r * K + k + 4);
    float vv[8] = {v0.x, v0.y, v0.z, v0.w, v1.x, v1.y, v1.z, v1.w};
    u16x8 hh, ll;
    #pragma unroll
    for (int j = 0; j < 8; ++j) {
        float x = vv[j];
        if (BN) x = fmaxf(fmaf(x, scs[k + j], shs[k + j]), 0.0f);
        unsigned short hi, lo; split2(x, hi, lo);
        hh[j] = hi; ll[j] = lo;
    }
    const int off = pk_off(r, k, K);
    *reinterpret_cast<u16x8*>(dh + off) = hh;
    *reinterpret_cast<u16x8*>(dl + off) = ll;
}

// ---------------- fused MFMA GEMM + oblivious-tree layer (LDS-staged, double-buffered) ----------------
// Block: 256 thr = 4 waves; tile 128 rows x 96 cols (16 trees); wave = 32 rows x 96 cols.
// Per K-step (32 k): stage A (16KB) + B (12KB) into LDS via global_load_lds (28 x 1KB chunks,
// 7 per wave), double-buffered; fragments read back as conflict-free ds_read_b128 (base+lane*16).
// Issue next step's stage BEFORE computing current (T3 minimal 2-phase).
template<int K>
__global__ __launch_bounds__(256)
void gemm_tree_mfma_kernel(const unsigned short* __restrict__ Ah, const unsigned short* __restrict__ Al,
                           const unsigned short* __restrict__ Bh, const unsigned short* __restrict__ Bl,
                           const float* __restrict__ th, const float* __restrict__ lt,
                           const float* __restrict__ lr,
                           float* __restrict__ h, float* __restrict__ bsum, float* __restrict__ bsq) {
    __shared__ alignas(16) char pool[57344];  // [Abuf0 16K][Abuf1 16K][Bbuf0 12K][Bbuf1 12K]; reused as sel transpose tile
    __shared__ float lrs[16 * 66];
    __shared__ float ths[96], es[96];
    __shared__ float red1[4][16], red2[4][16];

    const int tid = threadIdx.x;
    const int wv = tid >> 6, l = tid & 63;

    // XCD-aware swizzle (heuristic: linear id % 8 ~ XCD). Each XCD gets 8 row-tiles x all 8
    // column-tiles -> per-XCD L2 working set: A 1MB + B 0.8MB (layer1). Bijective.
    const int id  = blockIdx.x;
    const int xcd = id & 7, j = id >> 3;
    const int bx  = j & 7;                  // column block (16 trees)
    const int by  = (xcd << 3) | (j >> 3);  // row block (128 rows)

    const int tree_base = bx * 16;
    const int nbB = bx * 6;                 // B row-frag base
    const int bm  = by * 128;
    const int rbB = by * 8;                 // A row-frag base

    for (int q = tid; q < 1024; q += 256)
        lrs[(q >> 6) * 66 + (q & 63)] = lr[tree_base * 64 + q];
    if (tid < 96) {
        ths[tid] = th[tree_base * 6 + tid];
        es[tid]  = expf(lt[tree_base * 6 + tid]);
    }

    f32x4 acc[2][6];
    #pragma unroll
    for (int i = 0; i < 2; ++i)
        #pragma unroll
        for (int jj = 0; jj < 6; ++jj)
            acc[i][jj] = f32x4{0.f, 0.f, 0.f, 0.f};

    // per-wave staging descriptors: 7 chunks of 1KB each (A: 16 chunks, B: 12 chunks per block)
    const unsigned short* ssrc[7];
    int sdst[7], sstr[7];
    #pragma unroll
    for (int i = 0; i < 7; ++i) {
        const int c = wv * 7 + i;
        if (c < 16) {                       // A chunks: 0..7 = hi frag, 8..15 = lo frag
            const int f = c & 7;
            ssrc[i] = ((c < 8) ? Ah : Al) + (size_t)(rbB + f) * (K * 16) + l * 8;
            sdst[i] = c * 1024;
            sstr[i] = 16384;
        } else {                            // B chunks: 0..5 = hi frag, 6..11 = lo frag
            const int cc = c - 16;
            const int f = (cc < 6) ? cc : (cc - 6);
            ssrc[i] = ((cc < 6) ? Bh : Bl) + (size_t)(nbB + f) * (K * 16) + l * 8;
            sdst[i] = 32768 + cc * 1024;
            sstr[i] = 12288;
        }
    }

    auto stage = [&](int bufv, int ksv) {
        #pragma unroll
        for (int i = 0; i < 7; ++i)
            __builtin_amdgcn_global_load_lds(
                (const __attribute__((address_space(1))) unsigned int*)(ssrc[i] + ksv * 512),
                (__attribute__((address_space(3))) unsigned int*)(pool + sdst[i] + bufv * sstr[i]),
                16, 0, 0);
    };

    constexpr int NS = K / 32;
    int cur = 0;
    stage(0, 0);
    __syncthreads();                         // vmcnt(0) drain -> buf0 ready

    const int wv2 = wv * 2, l16 = l * 16;
    for (int ks = 0; ks < NS; ++ks) {
        if (ks + 1 < NS) stage(cur ^ 1, ks + 1);   // async prefetch next step
        const char* ab = pool + cur * 16384;
        const char* bb = pool + 32768 + cur * 12288;
        const bf16x8 a0h = *(const bf16x8*)(ab + (wv2    ) * 1024 + l16);
        const bf16x8 a1h = *(const bf16x8*)(ab + (wv2 + 1) * 1024 + l16);
        const bf16x8 a0l = *(const bf16x8*)(ab + (wv2 + 8) * 1024 + l16);
        const bf16x8 a1l = *(const bf16x8*)(ab + (wv2 + 9) * 1024 + l16);
        #pragma unroll
        for (int nf = 0; nf < 6; ++nf) {
            const bf16x8 bh = *(const bf16x8*)(bb + (nf    ) * 1024 + l16);
            const bf16x8 bl = *(const bf16x8*)(bb + (nf + 6) * 1024 + l16);
            acc[0][nf] = __builtin_amdgcn_mfma_f32_16x16x32_bf16(a0l, bh, acc[0][nf], 0, 0, 0);
            acc[0][nf] = __builtin_amdgcn_mfma_f32_16x16x32_bf16(a0h, bl, acc[0][nf], 0, 0, 0);
            acc[0][nf] = __builtin_amdgcn_mfma_f32_16x16x32_bf16(a0h, bh, acc[0][nf], 0, 0, 0);
            acc[1][nf] = __builtin_amdgcn_mfma_f32_16x16x32_bf16(a1l, bh, acc[1][nf], 0, 0, 0);
            acc[1][nf] = __builtin_amdgcn_mfma_f32_16x16x32_bf16(a1h, bl, acc[1][nf], 0, 0, 0);
            acc[1][nf] = __builtin_amdgcn_mfma_f32_16x16x32_bf16(a1h, bh, acc[1][nf], 0, 0, 0);
        }
        __syncthreads();                     // all reads of cur done + next buf written
        cur ^= 1;
    }

    // ---- tree epilogue: pool reused as per-wave transpose tile (all staging/reads complete) ----
    float* selw = (float*)(pool + wv * 6656);   // 16 rows x 104 floats per wave
    const int t = l & 15, rg = l >> 4;          // D layout: col = lane&15, row = (lane>>4)*4+reg
    const int t6 = t * 6, t66 = t * 66;
    float s1 = 0.f, s2 = 0.f;

    #pragma unroll
    for (int fm = 0; fm < 2; ++fm) {
        #pragma unroll
        for (int nf = 0; nf < 6; ++nf)
            #pragma unroll
            for (int r = 0; r < 4; ++r)
                selw[(rg * 4 + r) * 104 + nf * 16 + t] = acc[fm][nf][r];
        // wave-local LDS RAW: DS pipe in-order per wave; compiler inserts lgkmcnt waits
        #pragma unroll
        for (int i = 0; i < 4; ++i) {
            const int row = rg + 4 * i;
            const float2 p0 = *reinterpret_cast<const float2*>(&selw[row * 104 + t6]);
            const float2 p1 = *reinterpret_cast<const float2*>(&selw[row * 104 + t6 + 2]);
            const float2 p2 = *reinterpret_cast<const float2*>(&selw[row * 104 + t6 + 4]);
            const float sv[6] = {p0.x, p0.y, p1.x, p1.y, p2.x, p2.y};
            float dec[6];
            #pragma unroll
            for (int d = 0; d < 6; ++d)
                dec[d] = sigmoidf_((sv[d] - ths[t6 + d]) * es[t6 + d]);

            float a1r[2], a2r[4], a3r[8], a4r[16], a5r[32];
            a1r[0] = 1.0f - dec[0]; a1r[1] = dec[0];
            #pragma unroll
            for (int q = 0; q < 2; ++q)  { a2r[2*q] = a1r[q]*(1.0f-dec[1]); a2r[2*q+1] = a1r[q]*dec[1]; }
            #pragma unroll
            for (int q = 0; q < 4; ++q)  { a3r[2*q] = a2r[q]*(1.0f-dec[2]); a3r[2*q+1] = a2r[q]*dec[2]; }
            #pragma unroll
            for (int q = 0; q < 8; ++q)  { a4r[2*q] = a3r[q]*(1.0f-dec[3]); a4r[2*q+1] = a3r[q]*dec[3]; }
            #pragma unroll
            for (int q = 0; q < 16; ++q) { a5r[2*q] = a4r[q]*(1.0f-dec[4]); a5r[2*q+1] = a4r[q]*dec[4]; }

            float out = 0.0f;
            const float d5 = dec[5], nd5 = 1.0f - dec[5];
            #pragma unroll
            for (int p = 0; p < 32; ++p) {
                const float2 lp = *reinterpret_cast<const float2*>(&lrs[t66 + 2 * p]);
                out += a5r[p] * (lp.x * nd5 + lp.y * d5);
            }

            h[(size_t)(bm + wv * 32 + fm * 16 + row) * TOUT + tree_base + t] = out;
            s1 += out;
            s2 += out * out;
        }
    }

    s1 += __shfl_down(s1, 32, 64); s1 += __shfl_down(s1, 16, 64);
    s2 += __shfl_down(s2, 32, 64); s2 += __shfl_down(s2, 16, 64);
    if (l < 16) { red1[wv][l] = s1; red2[wv][l] = s2; }
    __syncthreads();
    if (tid < 16) {
        const float S = red1[0][tid] + red1[1][tid] + red1[2][tid] + red1[3][tid];
        const float Q = red2[0][tid] + red2[1][tid] + red2[2][tid] + red2[3][tid];
        atomicAdd(&bsum[tree_base + tid], S);
        atomicAdd(&bsq[tree_base + tid], Q);
    }
}

// ---------------- final: BN(from raw stats)+ReLU -> [128x64] -> ReLU -> [64x1] ----------------
__global__ __launch_bounds__(256)
void final_kernel(const float* __restrict__ h2,
                  const float* __restrict__ bsum, const float* __restrict__ bsq,
                  const float* __restrict__ g, const float* __restrict__ be,
                  const float* __restrict__ w1, const float* __restrict__ b1,
                  const float* __restrict__ w2, const float* __restrict__ b2,
                  float* __restrict__ out) {
    __shared__ float Hs[32 * 64];
    __shared__ float Ws[128 * 64];
    __shared__ float w2s[64], b1s[64];
    __shared__ float scs[128], shs[128];

    const int tid = threadIdx.x;
    const int jt = tid & 15, mt = tid >> 4;
    const int j0 = jt * 4;
    const int bm = blockIdx.x * 64;

    if (tid < 128) {
        const float inv = 1.0f / (float)BATCH;
        const float mu = bsum[tid] * inv;
        float var = bsq[tid] * inv - mu * mu;
        var = fmaxf(var, 0.0f);
        const float s = g[tid] / sqrtf(var + BN_EPS);
        scs[tid] = s;
        shs[tid] = be[tid] - mu * s;
    }
    for (int q = tid * 4; q < 128 * 64; q += 1024)
        *reinterpret_cast<float4*>(&Ws[q]) = *reinterpret_cast<const float4*>(&w1[q]);
    if (tid < 64) { w2s[tid] = w2[tid]; b1s[tid] = b1[tid]; }

    float acc[4][4] = {};
    const int t7 = tid & 7;
    const int akk = t7 * 4;
    const int arow = tid >> 3;

    for (int k0 = 0; k0 < 128; k0 += 32) {
        __syncthreads();
        #pragma unroll
        for (int p = 0; p < 2; ++p) {
            const int r = p * 32 + arow;
            float4 v = *reinterpret_cast<const float4*>(&h2[(size_t)(bm + r) * 128 + k0 + akk]);
            v.x = fmaxf(fmaf(v.x, scs[k0 + akk + 0], shs[k0 + akk + 0]), 0.0f);
            v.y = fmaxf(fmaf(v.y, scs[k0 + akk + 1], shs[k0 + akk + 1]), 0.0f);
            v.z = fmaxf(fmaf(v.z, scs[k0 + akk + 2], shs[k0 + akk + 2]), 0.0f);
            v.w = fmaxf(fmaf(v.w, scs[k0 + akk + 3], shs[k0 + akk + 3]), 0.0f);
            const int base = akk * 64 + ((((r >> 2) ^ t7) << 2) | (r & 3));
            Hs[base      ] = v.x;
            Hs[base + 64 ] = v.y;
            Hs[base + 128] = v.z;
            Hs[base + 192] = v.w;
        }
        __syncthreads();
        #pragma unroll
        for (int kk = 0; kk < 32; ++kk) {
            const float4 hv = *reinterpret_cast<const float4*>(&Hs[kk * 64 + ((mt ^ (kk >> 2)) << 2)]);
            const float4 wv = *reinterpret_cast<const float4*>(&Ws[(k0 + kk) * 64 + j0]);
            const float hvv[4] = {hv.x, hv.y, hv.z, hv.w};
            const float wvv[4] = {wv.x, wv.y, wv.z, wv.w};
            #pragma unroll
            for (int i = 0; i < 4; ++i)
                #pragma unroll
                for (int jj = 0; jj < 4; ++jj)
                    acc[i][jj] = fmaf(hvv[i], wvv[jj], acc[i][jj]);
        }
    }

    const float b2v = b2[0];
    #pragma unroll
    for (int i = 0; i < 4; ++i) {
        float part = 0.0f;
        #pragma unroll
        for (int jj = 0; jj < 4; ++jj)
            part += fmaxf(acc[i][jj] + b1s[j0 + jj], 0.0f) * w2s[j0 + jj];
        part += __shfl_down(part, 8, 16);
        part += __shfl_down(part, 4, 16);
        part += __shfl_down(part, 2, 16);
        part += __shfl_down(part, 1, 16);
        if (jt == 0) out[bm + mt * 4 + i] = part + b2v;
    }
}

// ---------------- launch ----------------
extern "C" void kernel_launch(void* const* d_in, const int* in_sizes, int n_in,
                              void* d_out, int out_size, void* d_ws, size_t ws_size,
                              hipStream_t stream) {
    const float* x   = (const float*)d_in[0];
    const float* fs1 = (const float*)d_in[1];
    const float* th1 = (const float*)d_in[2];
    const float* lr1 = (const float*)d_in[3];
    const float* lt1 = (const float*)d_in[4];
    const float* g1  = (const float*)d_in[5];
    const float* be1 = (const float*)d_in[6];
    const float* fs2 = (const float*)d_in[7];
    const float* th2 = (const float*)d_in[8];
    const float* lr2 = (const float*)d_in[9];
    const float* lt2 = (const float*)d_in[10];
    const float* g2  = (const float*)d_in[11];
    const float* be2 = (const float*)d_in[12];
    const float* w1  = (const float*)d_in[13];
    const float* b1  = (const float*)d_in[14];
    const float* w2  = (const float*)d_in[15];
    const float* b2  = (const float*)d_in[16];

    float* ws    = (float*)d_ws;
    float* stats = ws;                        // 512: sum1 sq1 sum2 sq2
    float* h1    = ws + 1024;                 // 8192*128
    float* h2    = h1 + 1048576;              // 8192*128
    unsigned short* us  = (unsigned short*)(h2 + 1048576);
    unsigned short* w1h = us;                 // 768*256
    unsigned short* w1l = w1h + 196608;
    unsigned short* w2h = w1l + 196608;       // 768*128
    unsigned short* w2l = w2h + 98304;
    unsigned short* xh  = w2l + 98304;        // 8192*256
    unsigned short* xl  = xh + 2097152;
    unsigned short* h1h = xl + 2097152;       // 8192*128
    unsigned short* h1l = h1h + 1048576;
    float* out = (float*)d_out;

    softmax_pack_kernel<<<1536, 256, 0, stream>>>(fs1, fs2, w1h, w1l, w2h, w2l);
    convert_pack_kernel<256, false><<<1024, 256, 0, stream>>>(
        x, xh, xl, nullptr, nullptr, nullptr, nullptr, stats);

    gemm_tree_mfma_kernel<256><<<512, 256, 0, stream>>>(
        xh, xl, w1h, w1l, th1, lt1, lr1, h1, stats + 0, stats + 128);

    convert_pack_kernel<128, true><<<512, 256, 0, stream>>>(
        h1, h1h, h1l, stats + 0, stats + 128, g1, be1, nullptr);

    gemm_tree_mfma_kernel<128><<<512, 256, 0, stream>>>(
        h1h, h1l, w2h, w2l, th2, lt2, lr2, h2, stats + 256, stats + 384);

    final_kernel<<<BATCH / 64, 256, 0, stream>>>(
        h2, stats + 256, stats + 384, g2, be2, w1, b1, w2, b2, out);
}